// Round 3
// baseline (321.337 us; speedup 1.0000x reference)
//
#include <hip/hip_runtime.h>
#include <hip/hip_bf16.h>

typedef __attribute__((ext_vector_type(8)))  short short8;
typedef __attribute__((ext_vector_type(4)))  float floatx4;
typedef __attribute__((ext_vector_type(16))) float floatx16;

#define BB 32
#define CC 256
#define OO 256
#define KS 7
#define HH 31
#define WW 31
#define HO 25
#define PP 625
#define SS 49

#define SLAB_PITCH 40        // ushort elems per pos row: 32 ci + 8 pad = 80 B
// 96-p tile spans <= 11 x-rows (px=1..5 hit 11). 11 x 31 = 341.
#define SLAB_ROWS  341
#define P_TILE 96
#define NPX 7                // ceil(625/96)
#define KP 36                // klds pitch in floats (16B-aligned rows, bank-spread)

// wt4 layout: [s][cb][kh][o][16ci]  (elems per (s,cb) = 2*256*16 = 8192)
#define WT4_ELEMS  ((size_t)SS * 8 * 2 * CC * 16)        // 3,211,264
#define WT4_BYTES  (WT4_ELEMS * 2)                       // 6,422,528

static __device__ __forceinline__ unsigned pk2(float lo, float hi) {
    float2 f; f.x = lo; f.y = hi;
    __hip_bfloat162 h = __float22bfloat162_rn(f);   // v_cvt_pk_bf16_f32
    unsigned r;
    __builtin_memcpy(&r, &h, sizeof(r));
    return r;
}
static __device__ __forceinline__ float bflo(unsigned u) {
    return __builtin_bit_cast(float, u << 16);
}
static __device__ __forceinline__ float bfhi(unsigned u) {
    return __builtin_bit_cast(float, u & 0xffff0000u);
}

// modulated pack: 8 bf16 = bf16( wt[j] * k[j] )
static __device__ __forceinline__ uint4 modpack(uint4 wv, float4 k0, float4 k1) {
    float p0 = bflo(wv.x) * k0.x, p1 = bfhi(wv.x) * k0.y;
    float p2 = bflo(wv.y) * k0.z, p3 = bfhi(wv.y) * k0.w;
    float p4 = bflo(wv.z) * k1.x, p5 = bfhi(wv.z) * k1.y;
    float p6 = bflo(wv.w) * k1.z, p7 = bfhi(wv.w) * k1.w;
    uint4 r;
    r.x = pk2(p0, p1); r.y = pk2(p2, p3); r.z = pk2(p4, p5); r.w = pk2(p6, p7);
    return r;
}

// ---------------------------------------------------------------------------
// Prepass: w[o][c][s] f32 -> wt4[s][cb][kh][o][16] bf16. Grid 392 = (s*8+cb).
// ---------------------------------------------------------------------------
__global__ __launch_bounds__(256) void repack_w(const float* __restrict__ w,
                                                unsigned short* __restrict__ wt4) {
    const int bid = blockIdx.x;           // = s*8 + cb
    const int s = bid >> 3, cb = bid & 7;
    const int o = threadIdx.x;
    const float* src = w + ((size_t)o * CC + cb * 32) * SS + s;
    float v[32];
#pragma unroll
    for (int ci = 0; ci < 32; ++ci) v[ci] = src[(size_t)ci * SS];
#pragma unroll
    for (int kh = 0; kh < 2; ++kh) {
        unsigned short* dst = wt4 + ((size_t)bid * 2 + kh) * (CC * 16) + o * 16;
        uint4 p0, p1;
        p0.x = pk2(v[kh*16+0], v[kh*16+1]);  p0.y = pk2(v[kh*16+2], v[kh*16+3]);
        p0.z = pk2(v[kh*16+4], v[kh*16+5]);  p0.w = pk2(v[kh*16+6], v[kh*16+7]);
        p1.x = pk2(v[kh*16+8], v[kh*16+9]);  p1.y = pk2(v[kh*16+10], v[kh*16+11]);
        p1.z = pk2(v[kh*16+12], v[kh*16+13]); p1.w = pk2(v[kh*16+14], v[kh*16+15]);
        *(uint4*)(dst)     = p0;
        *(uint4*)(dst + 8) = p1;
    }
}

// ---------------------------------------------------------------------------
// Fused main kernel: block = 128o x 96p of one batch, 4 waves o-split
// (wave wid owns o-range [oy*128 + wid*32, +32), all 49 s, acc 3x16).
// Per s-step per wave: 2 global b128 A (wt4, L2-hot since wt4 is only
// 6.4 MB and b-independent), in-register modulation (modpack, 40 VALU),
// 6 ds b128 B, 4 ds b128 k (broadcast), 6x mfma_32x32x16.
// Grid 448 = 32b x 2oy x 7px -> fully co-resident in one round at
// 3 blocks/CU (launch_bounds(256,3): reg cap ~170, acc=48 fits).
// id decode puts oy on XCD halves so each XCD L2 holds one 3.2 MB wt4 slice.
// No k-split -> no epilogue reduction; direct store.
// ---------------------------------------------------------------------------
__global__ __launch_bounds__(256, 3) void dwconv_fused(
        const float* __restrict__ x, const unsigned short* __restrict__ wt4,
        const float* __restrict__ kern, const float* __restrict__ bias,
        float* __restrict__ out) {
    __shared__ unsigned short slab[SLAB_ROWS * SLAB_PITCH];   // 27280 B
    __shared__ float klds[SS * KP];                           // 7056 B

    const int tid = threadIdx.x;
    const int id = blockIdx.x;
    // id = q*8 + r; oy = r>>2 (XCD halves), m = q*4 + (r&3) = b*7 + px
    const int q = id >> 3, r = id & 7;
    const int oy = r >> 2;
    const int m = q * 4 + (r & 3);            // 0..223
    const int b = m / NPX, px = m - (m / NPX) * NPX;

    const int p0 = px * P_TILE;
    const int h0 = p0 / HO;
    const int pmax = (p0 + P_TILE - 1 < PP - 1) ? p0 + P_TILE - 1 : PP - 1;
    const int rows = pmax / HO - h0 + 7;          // <= 11
    const int npos = rows * WW;

    const int lane = tid & 63, wid = tid >> 6;
    const int l32 = lane & 31, half = lane >> 5;

    // B-fragment LDS offsets (ushort elems) for 3 p-subtiles of 32
    int bOff[3];
#pragma unroll
    for (int ph = 0; ph < 3; ++ph) {
        int p = p0 + ph * 32 + l32;
        if (p > PP - 1) p = PP - 1;               // clamp; store guarded later
        int h = p / HO, ww_ = p - h * HO;
        bOff[ph] = ((h - h0) * WW + ww_) * SLAB_PITCH + half * 8;
    }

    // A base: this wave's o-range; frag(kh) = +kh*4096; per-s stride 65536;
    // per-cb offset cb*8192  (wt4[s][cb][kh][o][16])
    const unsigned short* wbase = wt4
        + (size_t)(oy * 128 + wid * 32 + l32) * 16 + half * 8;

    floatx16 acc[3];
#pragma unroll
    for (int ph = 0; ph < 3; ++ph)
#pragma unroll
        for (int rr = 0; rr < 16; ++rr) acc[ph][rr] = 0.f;

    for (int cb = 0; cb < 8; ++cb) {
        __syncthreads();   // prior compute done: slab/klds safe to overwrite
        // ---- stage x slab: slab[pos][ci] bf16, 4 waves x 8 channels ----
        {
            const float* xsrc = x + ((size_t)(b * CC + cb * 32 + wid * 8)) * (HH * WW)
                                  + h0 * WW;
#pragma unroll
            for (int it = 0; it < 6; ++it) {
                int pos = lane + it * 64;
                if (pos < npos) {
                    float v[8];
#pragma unroll
                    for (int j = 0; j < 8; ++j) v[j] = xsrc[j * (HH * WW) + pos];
                    uint4 pkt;
                    pkt.x = pk2(v[0], v[1]); pkt.y = pk2(v[2], v[3]);
                    pkt.z = pk2(v[4], v[5]); pkt.w = pk2(v[6], v[7]);
                    *(uint4*)(slab + pos * SLAB_PITCH + wid * 8) = pkt;
                }
            }
        }
        // ---- stage k table: klds[s][c] f32 for this (b, cb) ----
        {
            const float* ksrc = kern + ((size_t)(b * CC + cb * 32)) * SS;
#pragma unroll
            for (int it = 0; it < 7; ++it) {
                int f = tid + it * 256;
                if (f < 32 * SS) {
                    int c = f / SS, s = f - c * SS;
                    klds[s * KP + c] = ksrc[f];
                }
            }
        }
        __syncthreads();

        const unsigned short* aptr = wbase + (size_t)cb * 8192;   // s = 0

        uint4 wa0 = *(const uint4*)(aptr);          // kh0
        uint4 wa1 = *(const uint4*)(aptr + 4096);   // kh1

        int kk = 0, ll = 0;
        for (int si = 0; si < SS; ++si) {
            // prefetch s+1 A-frags (L2-hot wt4)
            uint4 wn0, wn1;
            if (si + 1 < SS) {
                aptr += 65536;
                wn0 = *(const uint4*)(aptr);
                wn1 = *(const uint4*)(aptr + 4096);
            } else {
                wn0 = wa0; wn1 = wa1;
            }

            // k values for this s: c = kh*16 + half*8 + j  (broadcast reads)
            const float* kp = klds + si * KP;
            float4 k0a = *(const float4*)(kp + half * 8);
            float4 k0b = *(const float4*)(kp + half * 8 + 4);
            float4 k1a = *(const float4*)(kp + 16 + half * 8);
            float4 k1b = *(const float4*)(kp + 16 + half * 8 + 4);

            const unsigned short* slabS = slab + (kk * WW + ll) * SLAB_PITCH;
            short8 sb00 = *(const short8*)(slabS + bOff[0]);        // ph0 kh0
            short8 sb01 = *(const short8*)(slabS + bOff[0] + 16);   // ph0 kh1
            short8 sb10 = *(const short8*)(slabS + bOff[1]);        // ph1 kh0
            short8 sb11 = *(const short8*)(slabS + bOff[1] + 16);   // ph1 kh1
            short8 sb20 = *(const short8*)(slabS + bOff[2]);        // ph2 kh0
            short8 sb21 = *(const short8*)(slabS + bOff[2] + 16);   // ph2 kh1

            short8 a0 = __builtin_bit_cast(short8, modpack(wa0, k0a, k0b)); // kh0
            short8 a1 = __builtin_bit_cast(short8, modpack(wa1, k1a, k1b)); // kh1

            acc[0] = __builtin_amdgcn_mfma_f32_32x32x16_bf16(a0, sb00, acc[0], 0, 0, 0);
            acc[1] = __builtin_amdgcn_mfma_f32_32x32x16_bf16(a0, sb10, acc[1], 0, 0, 0);
            acc[2] = __builtin_amdgcn_mfma_f32_32x32x16_bf16(a0, sb20, acc[2], 0, 0, 0);
            acc[0] = __builtin_amdgcn_mfma_f32_32x32x16_bf16(a1, sb01, acc[0], 0, 0, 0);
            acc[1] = __builtin_amdgcn_mfma_f32_32x32x16_bf16(a1, sb11, acc[1], 0, 0, 0);
            acc[2] = __builtin_amdgcn_mfma_f32_32x32x16_bf16(a1, sb21, acc[2], 0, 0, 0);

            wa0 = wn0; wa1 = wn1;
            if (++ll == KS) { ll = 0; ++kk; }
        }
    }

    // ---- epilogue: direct store (no k-split reduction) ----
    // C/D 32x32 mapping: col = l32 (p), row = (r&3) + 8*(r>>2) + 4*half (o)
    const int ow0 = oy * 128 + wid * 32;
#pragma unroll
    for (int c = 0; c < 4; ++c) {
        const int ob = ow0 + c * 8 + 4 * half;
        const float4 bv = *(const float4*)(bias + ob);
#pragma unroll
        for (int ph = 0; ph < 3; ++ph) {
            const int p = p0 + ph * 32 + l32;
            if (p < PP) {
                out[((size_t)(b * OO + ob + 0)) * PP + p] = acc[ph][4*c+0] + bv.x;
                out[((size_t)(b * OO + ob + 1)) * PP + p] = acc[ph][4*c+1] + bv.y;
                out[((size_t)(b * OO + ob + 2)) * PP + p] = acc[ph][4*c+2] + bv.z;
                out[((size_t)(b * OO + ob + 3)) * PP + p] = acc[ph][4*c+3] + bv.w;
            }
        }
    }
}

// ---------------------------------------------------------------------------
// Last-resort fallback: naive but correct (ws too small for wt4).
// ---------------------------------------------------------------------------
__global__ __launch_bounds__(256) void dwconv_naive(
        const float* __restrict__ x, const float* __restrict__ kern,
        const float* __restrict__ w, const float* __restrict__ bias,
        float* __restrict__ out) {
    const int idx = blockIdx.x * 256 + threadIdx.x;
    if (idx >= BB * OO * PP) return;
    const int p = idx % PP;
    const int o = (idx / PP) % OO;
    const int b = idx / (PP * OO);
    const int h = p / HO;
    const int wq = p - h * HO;
    float acc = 0.f;
    for (int c = 0; c < CC; ++c) {
        const float* xp = x + ((size_t)(b * CC + c)) * (HH * WW) + h * WW + wq;
        const float* kp = kern + ((size_t)b * CC + c) * SS;
        const float* wp = w + ((size_t)o * CC + c) * SS;
#pragma unroll
        for (int s = 0; s < SS; ++s) {
            const int kk = s / KS;
            const int ll = s - kk * KS;
            acc += xp[kk * WW + ll] * kp[s] * wp[s];
        }
    }
    out[idx] = acc + bias[o];
}

extern "C" void kernel_launch(void* const* d_in, const int* in_sizes, int n_in,
                              void* d_out, int out_size, void* d_ws, size_t ws_size,
                              hipStream_t stream) {
    const float* x    = (const float*)d_in[0];
    const float* kern = (const float*)d_in[1];
    const float* w    = (const float*)d_in[2];
    const float* bias = (const float*)d_in[3];
    float* out = (float*)d_out;

    if (ws_size >= WT4_BYTES) {
        unsigned short* wt4 = (unsigned short*)d_ws;
        repack_w<<<dim3(SS * 8), dim3(256), 0, stream>>>(w, wt4);
        dwconv_fused<<<dim3(448), dim3(256), 0, stream>>>(x, wt4, kern, bias, out);
    } else {
        const int total = BB * OO * PP;
        dwconv_naive<<<dim3((total + 255) / 256), dim3(256), 0, stream>>>(
            x, kern, w, bias, out);
    }
}

// Round 4
// 292.820 us; speedup vs baseline: 1.0974x; 1.0974x over previous
//
#include <hip/hip_runtime.h>
#include <hip/hip_fp16.h>

typedef _Float16 half8 __attribute__((ext_vector_type(8)));
typedef __attribute__((ext_vector_type(4)))  float floatx4;
typedef __attribute__((ext_vector_type(16))) float floatx16;

#define BB 32
#define CC 256
#define OO 256
#define KS 7
#define HH 31
#define WW 31
#define HO 25
#define PP 625
#define SS 49

#define SLAB_PITCH 40        // ushort elems per pos row: 32 ci + 8 pad = 80 B
// 64-p tile spans <= 10 x-rows. 10 x 31 = 310.
#define SLAB_ROWS  310
#define P_TILE 64
#define NPX 10               // ceil(625/64)
#define KPD 20               // klds pitch in dwords (16 half2 + 4 pad, 16B-aligned)

// wt4 layout: [s][cb][kh][o][16ci]  (elems per (s,cb) = 2*256*16 = 8192)
#define WT4_ELEMS  ((size_t)SS * 8 * 2 * CC * 16)        // 3,211,264
#define WT4_BYTES  (WT4_ELEMS * 2)                       // 6,422,528

static __device__ __forceinline__ unsigned pk2h(float lo, float hi) {
    __half2 h = __floats2half2_rn(lo, hi);    // v_cvt_pkrtz_f16_f32
    unsigned r;
    __builtin_memcpy(&r, &h, sizeof(r));
    return r;
}
static __device__ __forceinline__ unsigned mulh2(unsigned a, unsigned b) {
    __half2 x, y;
    __builtin_memcpy(&x, &a, 4); __builtin_memcpy(&y, &b, 4);
    __half2 r = __hmul2(x, y);                // v_pk_mul_f16
    unsigned u;
    __builtin_memcpy(&u, &r, 4);
    return u;
}
// modulated A-fragment: 8 fp16 = w[j] * k[j] via 4x v_pk_mul_f16
static __device__ __forceinline__ half8 mod8(uint4 w, uint4 k) {
    uint4 r;
    r.x = mulh2(w.x, k.x); r.y = mulh2(w.y, k.y);
    r.z = mulh2(w.z, k.z); r.w = mulh2(w.w, k.w);
    return __builtin_bit_cast(half8, r);
}

// ---------------------------------------------------------------------------
// Prepass: w[o][c][s] f32 -> wt4[s][cb][kh][o][16] fp16. Grid 392 = (s*8+cb).
// ---------------------------------------------------------------------------
__global__ __launch_bounds__(256) void repack_w(const float* __restrict__ w,
                                                unsigned short* __restrict__ wt4) {
    const int bid = blockIdx.x;           // = s*8 + cb
    const int s = bid >> 3, cb = bid & 7;
    const int o = threadIdx.x;
    const float* src = w + ((size_t)o * CC + cb * 32) * SS + s;
    float v[32];
#pragma unroll
    for (int ci = 0; ci < 32; ++ci) v[ci] = src[(size_t)ci * SS];
#pragma unroll
    for (int kh = 0; kh < 2; ++kh) {
        unsigned short* dst = wt4 + ((size_t)bid * 2 + kh) * (CC * 16) + o * 16;
        uint4 p0, p1;
        p0.x = pk2h(v[kh*16+0], v[kh*16+1]);  p0.y = pk2h(v[kh*16+2], v[kh*16+3]);
        p0.z = pk2h(v[kh*16+4], v[kh*16+5]);  p0.w = pk2h(v[kh*16+6], v[kh*16+7]);
        p1.x = pk2h(v[kh*16+8], v[kh*16+9]);  p1.y = pk2h(v[kh*16+10], v[kh*16+11]);
        p1.z = pk2h(v[kh*16+12], v[kh*16+13]); p1.w = pk2h(v[kh*16+14], v[kh*16+15]);
        *(uint4*)(dst)     = p0;
        *(uint4*)(dst + 8) = p1;
    }
}

// ---------------------------------------------------------------------------
// Fused main: block = 128o x 64p of one batch, 4 waves o-split
// (wave wid owns 32 o-rows, all 49 s, acc 2x16 = 32 regs).
// Per s-step per wave: 2 global b128 A (wt4, L2-hot, 2-deep prefetch),
// fp16 in-register modulation (8x v_pk_mul_f16), 2 broadcast k reads,
// 4 ds b128 B, 4x mfma_32x32x16_f16.
// Grid 640 = 32b x 2oy x 10px, launch_bounds(256,4): 2-3 blocks/CU
// co-resident -> 2-3 waves/SIMD (R3 had 1.6: the measured bottleneck).
// oy = id&1 pins each XCD's L2 to one 3.2 MB wt4 o-slice.
// ---------------------------------------------------------------------------
__global__ __launch_bounds__(256, 4) void dwconv_fused(
        const float* __restrict__ x, const unsigned short* __restrict__ wt4,
        const float* __restrict__ kern, const float* __restrict__ bias,
        float* __restrict__ out) {
    __shared__ unsigned short slab[SLAB_ROWS * SLAB_PITCH];   // 24800 B
    __shared__ unsigned klds[SS * KPD];                       // 3920 B

    const int tid = threadIdx.x;
    const int id = blockIdx.x;
    // oy on XCD parity; m enumerates (b, px)
    const int oy = id & 1;
    const int m = id >> 1;                    // 0..319
    const int b = m / NPX, px = m - (m / NPX) * NPX;

    const int p0 = px * P_TILE;
    const int h0 = p0 / HO;
    const int pmax = (p0 + P_TILE - 1 < PP - 1) ? p0 + P_TILE - 1 : PP - 1;
    const int rows = pmax / HO - h0 + 7;          // <= 10
    const int npos = rows * WW;

    const int lane = tid & 63, wid = tid >> 6;
    const int l32 = lane & 31, half = lane >> 5;

    // B-fragment LDS offsets (ushort elems) for 2 p-subtiles of 32
    int bOff[2];
#pragma unroll
    for (int ph = 0; ph < 2; ++ph) {
        int p = p0 + ph * 32 + l32;
        if (p > PP - 1) p = PP - 1;               // clamp; store guarded later
        int h = p / HO, ww_ = p - h * HO;
        bOff[ph] = ((h - h0) * WW + ww_) * SLAB_PITCH + half * 8;
    }

    // A base: this wave's 32 o-rows; frag(kh) = +kh*4096; per-s stride 65536;
    // per-cb offset cb*8192  (wt4[s][cb][kh][o][16])
    const unsigned short* wbase = wt4
        + (size_t)(oy * 128 + wid * 32 + l32) * 16 + half * 8;

    floatx16 acc[2];
#pragma unroll
    for (int ph = 0; ph < 2; ++ph)
#pragma unroll
        for (int rr = 0; rr < 16; ++rr) acc[ph][rr] = 0.f;

    for (int cb = 0; cb < 8; ++cb) {
        __syncthreads();   // prior compute done: slab/klds safe to overwrite
        // ---- stage x slab: slab[pos][ci] fp16, 4 waves x 8 channels ----
        {
            const float* xsrc = x + ((size_t)(b * CC + cb * 32 + wid * 8)) * (HH * WW)
                                  + h0 * WW;
#pragma unroll
            for (int it = 0; it < 5; ++it) {
                int pos = lane + it * 64;
                if (pos < npos) {
                    float v[8];
#pragma unroll
                    for (int j = 0; j < 8; ++j) v[j] = xsrc[j * (HH * WW) + pos];
                    uint4 pkt;
                    pkt.x = pk2h(v[0], v[1]); pkt.y = pk2h(v[2], v[3]);
                    pkt.z = pk2h(v[4], v[5]); pkt.w = pk2h(v[6], v[7]);
                    *(uint4*)(slab + pos * SLAB_PITCH + wid * 8) = pkt;
                }
            }
        }
        // ---- stage k table: klds[s][16 half2] for this (b, cb) ----
        {
            const float* ksrc = kern + ((size_t)(b * CC + cb * 32)) * SS;
#pragma unroll
            for (int it = 0; it < 4; ++it) {
                int f = tid + it * 256;
                if (f < 16 * SS) {
                    int s = f >> 4, pr = f & 15;
                    float v0 = ksrc[(size_t)(pr * 2) * SS + s];
                    float v1 = ksrc[(size_t)(pr * 2 + 1) * SS + s];
                    klds[s * KPD + pr] = pk2h(v0, v1);
                }
            }
        }
        __syncthreads();

        const unsigned short* aptr = wbase + (size_t)cb * 8192;   // s = 0
        uint4 a0k0 = *(const uint4*)(aptr);                 // s,   kh0
        uint4 a0k1 = *(const uint4*)(aptr + 4096);          // s,   kh1
        uint4 a1k0 = *(const uint4*)(aptr + 65536);         // s+1, kh0
        uint4 a1k1 = *(const uint4*)(aptr + 65536 + 4096);  // s+1, kh1

        int kk = 0, ll = 0;
        for (int si = 0; si < SS; ++si) {
            // prefetch s+2 A-frags (L2-hot wt4)
            uint4 n0, n1;
            if (si + 2 < SS) {
                const unsigned short* p2 = aptr + 2 * 65536;
                n0 = *(const uint4*)(p2);
                n1 = *(const uint4*)(p2 + 4096);
            } else {
                n0 = a1k0; n1 = a1k1;
            }

            // k for this s: broadcast 16B reads per kh (channels kh*16+half*8..+7)
            uint4 kv0 = *(const uint4*)(klds + si * KPD + half * 4);
            uint4 kv1 = *(const uint4*)(klds + si * KPD + 8 + half * 4);

            const unsigned short* slabS = slab + (kk * WW + ll) * SLAB_PITCH;
            half8 b00 = *(const half8*)(slabS + bOff[0]);        // ph0 kh0
            half8 b01 = *(const half8*)(slabS + bOff[0] + 16);   // ph0 kh1
            half8 b10 = *(const half8*)(slabS + bOff[1]);        // ph1 kh0
            half8 b11 = *(const half8*)(slabS + bOff[1] + 16);   // ph1 kh1

            half8 a0 = mod8(a0k0, kv0);   // kh0: 4x v_pk_mul_f16
            half8 a1 = mod8(a0k1, kv1);   // kh1

            acc[0] = __builtin_amdgcn_mfma_f32_32x32x16_f16(a0, b00, acc[0], 0, 0, 0);
            acc[1] = __builtin_amdgcn_mfma_f32_32x32x16_f16(a0, b10, acc[1], 0, 0, 0);
            acc[0] = __builtin_amdgcn_mfma_f32_32x32x16_f16(a1, b01, acc[0], 0, 0, 0);
            acc[1] = __builtin_amdgcn_mfma_f32_32x32x16_f16(a1, b11, acc[1], 0, 0, 0);

            a0k0 = a1k0; a0k1 = a1k1; a1k0 = n0; a1k1 = n1;
            aptr += 65536;
            if (++ll == KS) { ll = 0; ++kk; }
        }
    }

    // ---- epilogue: direct store (no k-split reduction) ----
    // C/D 32x32 mapping: col = l32 (p), row = (reg&3) + 8*(reg>>2) + 4*half (o)
    const int ow0 = oy * 128 + wid * 32;
#pragma unroll
    for (int c = 0; c < 4; ++c) {
        const int ob = ow0 + c * 8 + 4 * half;
        const float4 bv = *(const float4*)(bias + ob);
#pragma unroll
        for (int ph = 0; ph < 2; ++ph) {
            const int p = p0 + ph * 32 + l32;
            if (p < PP) {
                out[((size_t)(b * OO + ob + 0)) * PP + p] = acc[ph][4*c+0] + bv.x;
                out[((size_t)(b * OO + ob + 1)) * PP + p] = acc[ph][4*c+1] + bv.y;
                out[((size_t)(b * OO + ob + 2)) * PP + p] = acc[ph][4*c+2] + bv.z;
                out[((size_t)(b * OO + ob + 3)) * PP + p] = acc[ph][4*c+3] + bv.w;
            }
        }
    }
}

// ---------------------------------------------------------------------------
// Last-resort fallback: naive but correct (ws too small for wt4).
// ---------------------------------------------------------------------------
__global__ __launch_bounds__(256) void dwconv_naive(
        const float* __restrict__ x, const float* __restrict__ kern,
        const float* __restrict__ w, const float* __restrict__ bias,
        float* __restrict__ out) {
    const int idx = blockIdx.x * 256 + threadIdx.x;
    if (idx >= BB * OO * PP) return;
    const int p = idx % PP;
    const int o = (idx / PP) % OO;
    const int b = idx / (PP * OO);
    const int h = p / HO;
    const int wq = p - h * HO;
    float acc = 0.f;
    for (int c = 0; c < CC; ++c) {
        const float* xp = x + ((size_t)(b * CC + c)) * (HH * WW) + h * WW + wq;
        const float* kp = kern + ((size_t)b * CC + c) * SS;
        const float* wp = w + ((size_t)o * CC + c) * SS;
#pragma unroll
        for (int s = 0; s < SS; ++s) {
            const int kk = s / KS;
            const int ll = s - kk * KS;
            acc += xp[kk * WW + ll] * kp[s] * wp[s];
        }
    }
    out[idx] = acc + bias[o];
}

extern "C" void kernel_launch(void* const* d_in, const int* in_sizes, int n_in,
                              void* d_out, int out_size, void* d_ws, size_t ws_size,
                              hipStream_t stream) {
    const float* x    = (const float*)d_in[0];
    const float* kern = (const float*)d_in[1];
    const float* w    = (const float*)d_in[2];
    const float* bias = (const float*)d_in[3];
    float* out = (float*)d_out;

    if (ws_size >= WT4_BYTES) {
        unsigned short* wt4 = (unsigned short*)d_ws;
        repack_w<<<dim3(SS * 8), dim3(256), 0, stream>>>(w, wt4);
        dwconv_fused<<<dim3(640), dim3(256), 0, stream>>>(x, wt4, kern, bias, out);
    } else {
        const int total = BB * OO * PP;
        dwconv_naive<<<dim3((total + 255) / 256), dim3(256), 0, stream>>>(
            x, kern, w, bias, out);
    }
}